// Round 2
// baseline (315.437 us; speedup 1.0000x reference)
//
#include <hip/hip_runtime.h>

#define NC 10     // clusters
#define EMB 64
#define DD 1024
#define NP 4096   // patches per bag
#define NB 8      // batch

// ---------------- Kernel 1: e = relu(data @ W1^T + b1), fused segment sum ---
// grid = NB*64 blocks (64 patch-tiles of 64 per bag), 256 threads.
__global__ __launch_bounds__(256) void embed_seg_kernel(
    const float* __restrict__ data, const int* __restrict__ labels,
    const float* __restrict__ W1, const float* __restrict__ b1,
    float* __restrict__ sums, float* __restrict__ counts)
{
    __shared__ float As[64][66];   // 64 patches x 64 k (pad 2)
    __shared__ float Ws[64][66];   // 64 embs   x 64 k
    __shared__ float csum[NC][EMB];
    __shared__ float ccnt[NC];
    __shared__ int   labs[64];

    const int t  = threadIdx.x;
    const int b  = blockIdx.x >> 6;
    const int p0 = (blockIdx.x & 63) << 6;

    for (int i = t; i < NC * EMB; i += 256) (&csum[0][0])[i] = 0.f;
    if (t < NC) ccnt[t] = 0.f;
    if (t < 64) labs[t] = labels[b * NP + p0 + t];

    const float* Ab = data + ((size_t)(b * NP + p0)) * DD;

    const int tx = t & 15;        // emb quad
    const int ty = t >> 4;        // patch quad
    const int lr = t >> 4;        // staging row
    const int lc = (t & 15) << 2; // staging col (float4)

    float bias[4];
#pragma unroll
    for (int j = 0; j < 4; ++j) bias[j] = b1[(tx << 2) + j];

    float acc[4][4] = {};

    for (int kk = 0; kk < DD; kk += 64) {
        __syncthreads();
#pragma unroll
        for (int i = 0; i < 4; ++i) {
            const int r = lr + (i << 4);
            *(float4*)&As[r][lc] = *(const float4*)(Ab + (size_t)r * DD + kk + lc);
            *(float4*)&Ws[r][lc] = *(const float4*)(W1 + (size_t)r * DD + kk + lc);
        }
        __syncthreads();
#pragma unroll
        for (int k2 = 0; k2 < 32; ++k2) {
            const int k = k2 << 1;
            float2 av[4], wv[4];
#pragma unroll
            for (int i = 0; i < 4; ++i) {
                av[i] = *(const float2*)&As[(ty << 2) + i][k];
                wv[i] = *(const float2*)&Ws[(tx << 2) + i][k];
            }
#pragma unroll
            for (int i = 0; i < 4; ++i)
#pragma unroll
                for (int j = 0; j < 4; ++j) {
                    acc[i][j] = fmaf(av[i].x, wv[j].x, acc[i][j]);
                    acc[i][j] = fmaf(av[i].y, wv[j].y, acc[i][j]);
                }
        }
    }

    __syncthreads();
#pragma unroll
    for (int i = 0; i < 4; ++i) {
        const int lab = labs[(ty << 2) + i];
#pragma unroll
        for (int j = 0; j < 4; ++j) {
            float v = acc[i][j] + bias[j];
            v = v > 0.f ? v : 0.f;
            atomicAdd(&csum[lab][(tx << 2) + j], v);
        }
    }
    if (t < 64) atomicAdd(&ccnt[labs[t]], 1.0f);
    __syncthreads();
    for (int i = t; i < NC * EMB; i += 256)
        atomicAdd(&sums[b * NC * EMB + i], (&csum[0][0])[i]);
    if (t < NC) atomicAdd(&counts[b * NC + t], ccnt[t]);
}

// ---------------- Kernel 2: cluster means, attention, masked softmax, fc6 ---
// grid = NB blocks, 128 threads.
__global__ __launch_bounds__(128) void head_kernel(
    const float* __restrict__ sums, const float* __restrict__ counts,
    const float* __restrict__ Wa1, const float* __restrict__ ba1,
    const float* __restrict__ Wa2, const float* __restrict__ ba2,
    const float* __restrict__ Wf1, const float* __restrict__ bf1,
    const float* __restrict__ Wf2, const float* __restrict__ bf2,
    float* __restrict__ out)
{
    __shared__ float h[NC][EMB];
    __shared__ float mask[NC];
    __shared__ float att[NC][32];
    __shared__ float a_s[NC];
    __shared__ float A_s[NC];
    __shared__ float M_s[EMB];
    __shared__ float f_s[32];

    const int b = blockIdx.x;
    const int t = threadIdx.x;

    if (t < NC) {
        float cnt = counts[b * NC + t];
        mask[t] = cnt > 0.f ? 1.f : 0.f;
    }
    for (int i = t; i < NC * EMB; i += 128) {
        int c = i >> 6;
        float cnt = counts[b * NC + c];
        (&h[0][0])[i] = sums[b * NC * EMB + i] / fmaxf(cnt, 1.f);
    }
    __syncthreads();

    for (int task = t; task < NC * 32; task += 128) {
        int c = task >> 5, hh = task & 31;
        float s = ba1[hh];
        for (int e = 0; e < EMB; ++e) s = fmaf(Wa1[hh * EMB + e], h[c][e], s);
        att[c][hh] = tanhf(s);
    }
    __syncthreads();

    if (t < NC) {
        float s = ba2[0];
        for (int hh = 0; hh < 32; ++hh) s = fmaf(Wa2[hh], att[t][hh], s);
        a_s[t] = s;
    }
    __syncthreads();

    if (t == 0) {
        // faithful to reference numeric trick
        float xmax = -1e30f;
        for (int c = 0; c < NC; ++c) {
            float xm = a_s[c] * mask[c] + (1.0f - 1.0f / (mask[c] + 1e-5f));
            xmax = fmaxf(xmax, xm);
        }
        float ex[NC], ssum = 0.f;
        for (int c = 0; c < NC; ++c) {
            ex[c] = expf(a_s[c] - xmax) * mask[c];
            ssum += ex[c];
        }
        for (int c = 0; c < NC; ++c) A_s[c] = ex[c] / ssum;
    }
    __syncthreads();

    if (t < EMB) {
        float s = 0.f;
        for (int c = 0; c < NC; ++c) s = fmaf(A_s[c], h[c][t], s);
        M_s[t] = s;
    }
    __syncthreads();

    if (t < 32) {
        float s = bf1[t];
        for (int e = 0; e < EMB; ++e) s = fmaf(Wf1[t * EMB + e], M_s[e], s);
        f_s[t] = fmaxf(s, 0.f);
    }
    __syncthreads();

    if (t == 0) {
        float s = bf2[0];
        for (int hh = 0; hh < 32; ++hh) s = fmaf(Wf2[hh], f_s[hh], s);
        out[b] = s;
    }
}

extern "C" void kernel_launch(void* const* d_in, const int* in_sizes, int n_in,
                              void* d_out, int out_size, void* d_ws, size_t ws_size,
                              hipStream_t stream)
{
    const float* data   = (const float*)d_in[0];
    const int*   labels = (const int*)  d_in[1];
    const float* W1     = (const float*)d_in[2];
    const float* b1     = (const float*)d_in[3];
    const float* Wa1    = (const float*)d_in[4];
    const float* ba1    = (const float*)d_in[5];
    const float* Wa2    = (const float*)d_in[6];
    const float* ba2    = (const float*)d_in[7];
    const float* Wf1    = (const float*)d_in[8];
    const float* bf1    = (const float*)d_in[9];
    const float* Wf2    = (const float*)d_in[10];
    const float* bf2    = (const float*)d_in[11];

    float* sums   = (float*)d_ws;                    // [NB][NC][EMB]
    float* counts = sums + NB * NC * EMB;            // [NB][NC]

    hipMemsetAsync(d_ws, 0, (size_t)(NB * NC * EMB + NB * NC) * sizeof(float), stream);

    embed_seg_kernel<<<NB * 64, 256, 0, stream>>>(data, labels, W1, b1, sums, counts);
    head_kernel<<<NB, 128, 0, stream>>>(sums, counts, Wa1, ba1, Wa2, ba2,
                                        Wf1, bf1, Wf2, bf2, (float*)d_out);
}

// Round 3
// 304.656 us; speedup vs baseline: 1.0354x; 1.0354x over previous
//
#include <hip/hip_runtime.h>

#define NC 10     // clusters
#define EMB 64
#define DD 1024
#define NP 4096   // patches per bag
#define NB 8      // batch

// ---------------- Kernel 1: e = relu(data @ W1^T + b1), fused segment sum ---
// grid = NB*64 blocks (64 patches per block), 512 threads = 8 waves.
// lane = patch (own-row LDS reads); wave w = emb range [8w, 8w+8).
// W1 accessed with wave-uniform indices -> scalar (SMEM) loads, zero VALU cost.
__global__ __launch_bounds__(512, 2) void embed_seg_kernel(
    const float* __restrict__ data, const int* __restrict__ labels,
    const float* __restrict__ W1, const float* __restrict__ b1,
    float* __restrict__ sums, float* __restrict__ counts)
{
    __shared__ float As[64][68];     // 64 patches x 64 k-chunk, stride 68 (272B, 16B-aligned)
    __shared__ float csum[NC][EMB];
    __shared__ float ccnt[NC];
    __shared__ int   labs[64];

    const int t    = threadIdx.x;
    const int lane = t & 63;
    const int w    = t >> 6;                 // wave id 0..7
    const int b    = blockIdx.x >> 6;
    const int p0   = (blockIdx.x & 63) << 6;

    for (int i = t; i < NC * EMB; i += 512) (&csum[0][0])[i] = 0.f;
    if (t < NC) ccnt[t] = 0.f;
    if (t < 64) labs[t] = labels[b * NP + p0 + t];

    // wave-uniform emb base -> forces W accesses onto the scalar pipe
    const int we = __builtin_amdgcn_readfirstlane(w << 3);
    const float* __restrict__ Wb = W1 + (size_t)we * DD;

    const float* Ab = data + (size_t)(b * NP + p0) * DD;

    // staging: thread -> (row = t>>3, col8 = (t&7)*8), 64x64 chunk
    const int srow = t >> 3;
    const int scol = (t & 7) << 3;

    float acc[8] = {};

    for (int kk = 0; kk < DD; kk += 64) {
        __syncthreads();
        float4 v0 = *(const float4*)(Ab + (size_t)srow * DD + kk + scol);
        float4 v1 = *(const float4*)(Ab + (size_t)srow * DD + kk + scol + 4);
        *(float4*)&As[srow][scol]     = v0;
        *(float4*)&As[srow][scol + 4] = v1;
        __syncthreads();
#pragma unroll 2
        for (int kq = 0; kq < 16; ++kq) {
            const float4 av = *(const float4*)&As[lane][kq << 2];
#pragma unroll
            for (int e = 0; e < 8; ++e) {
                const float4 wv = *(const float4*)(Wb + (size_t)e * DD + kk + (kq << 2));
                acc[e] = fmaf(av.x, wv.x, acc[e]);
                acc[e] = fmaf(av.y, wv.y, acc[e]);
                acc[e] = fmaf(av.z, wv.z, acc[e]);
                acc[e] = fmaf(av.w, wv.w, acc[e]);
            }
        }
    }

    __syncthreads();
    const int lab = labs[lane];
#pragma unroll
    for (int e = 0; e < 8; ++e) {
        float vv = fmaxf(acc[e] + b1[we + e], 0.f);
        atomicAdd(&csum[lab][we + e], vv);
    }
    if (w == 0) atomicAdd(&ccnt[lab], 1.0f);
    __syncthreads();
    for (int i = t; i < NC * EMB; i += 512)
        atomicAdd(&sums[b * NC * EMB + i], (&csum[0][0])[i]);
    if (t < NC) atomicAdd(&counts[b * NC + t], ccnt[t]);
}

// ---------------- Kernel 2: cluster means, attention, masked softmax, fc6 ---
// grid = NB blocks, 128 threads.
__global__ __launch_bounds__(128) void head_kernel(
    const float* __restrict__ sums, const float* __restrict__ counts,
    const float* __restrict__ Wa1, const float* __restrict__ ba1,
    const float* __restrict__ Wa2, const float* __restrict__ ba2,
    const float* __restrict__ Wf1, const float* __restrict__ bf1,
    const float* __restrict__ Wf2, const float* __restrict__ bf2,
    float* __restrict__ out)
{
    __shared__ float h[NC][EMB];
    __shared__ float mask[NC];
    __shared__ float att[NC][32];
    __shared__ float a_s[NC];
    __shared__ float A_s[NC];
    __shared__ float M_s[EMB];
    __shared__ float f_s[32];

    const int b = blockIdx.x;
    const int t = threadIdx.x;

    if (t < NC) {
        float cnt = counts[b * NC + t];
        mask[t] = cnt > 0.f ? 1.f : 0.f;
    }
    for (int i = t; i < NC * EMB; i += 128) {
        int c = i >> 6;
        float cnt = counts[b * NC + c];
        (&h[0][0])[i] = sums[b * NC * EMB + i] / fmaxf(cnt, 1.f);
    }
    __syncthreads();

    for (int task = t; task < NC * 32; task += 128) {
        int c = task >> 5, hh = task & 31;
        float s = ba1[hh];
        for (int e = 0; e < EMB; ++e) s = fmaf(Wa1[hh * EMB + e], h[c][e], s);
        att[c][hh] = tanhf(s);
    }
    __syncthreads();

    if (t < NC) {
        float s = ba2[0];
        for (int hh = 0; hh < 32; ++hh) s = fmaf(Wa2[hh], att[t][hh], s);
        a_s[t] = s;
    }
    __syncthreads();

    if (t == 0) {
        // faithful to reference numeric trick
        float xmax = -1e30f;
        for (int c = 0; c < NC; ++c) {
            float xm = a_s[c] * mask[c] + (1.0f - 1.0f / (mask[c] + 1e-5f));
            xmax = fmaxf(xmax, xm);
        }
        float ex[NC], ssum = 0.f;
        for (int c = 0; c < NC; ++c) {
            ex[c] = expf(a_s[c] - xmax) * mask[c];
            ssum += ex[c];
        }
        for (int c = 0; c < NC; ++c) A_s[c] = ex[c] / ssum;
    }
    __syncthreads();

    if (t < EMB) {
        float s = 0.f;
        for (int c = 0; c < NC; ++c) s = fmaf(A_s[c], h[c][t], s);
        M_s[t] = s;
    }
    __syncthreads();

    if (t < 32) {
        float s = bf1[t];
        for (int e = 0; e < EMB; ++e) s = fmaf(Wf1[t * EMB + e], M_s[e], s);
        f_s[t] = fmaxf(s, 0.f);
    }
    __syncthreads();

    if (t == 0) {
        float s = bf2[0];
        for (int hh = 0; hh < 32; ++hh) s = fmaf(Wf2[hh], f_s[hh], s);
        out[b] = s;
    }
}

extern "C" void kernel_launch(void* const* d_in, const int* in_sizes, int n_in,
                              void* d_out, int out_size, void* d_ws, size_t ws_size,
                              hipStream_t stream)
{
    const float* data   = (const float*)d_in[0];
    const int*   labels = (const int*)  d_in[1];
    const float* W1     = (const float*)d_in[2];
    const float* b1     = (const float*)d_in[3];
    const float* Wa1    = (const float*)d_in[4];
    const float* ba1    = (const float*)d_in[5];
    const float* Wa2    = (const float*)d_in[6];
    const float* ba2    = (const float*)d_in[7];
    const float* Wf1    = (const float*)d_in[8];
    const float* bf1    = (const float*)d_in[9];
    const float* Wf2    = (const float*)d_in[10];
    const float* bf2    = (const float*)d_in[11];

    float* sums   = (float*)d_ws;                    // [NB][NC][EMB]
    float* counts = sums + NB * NC * EMB;            // [NB][NC]

    hipMemsetAsync(d_ws, 0, (size_t)(NB * NC * EMB + NB * NC) * sizeof(float), stream);

    embed_seg_kernel<<<NB * 64, 512, 0, stream>>>(data, labels, W1, b1, sums, counts);
    head_kernel<<<NB, 128, 0, stream>>>(sums, counts, Wa1, ba1, Wa2, ba2,
                                        Wf1, bf1, Wf2, bf2, (float*)d_out);
}